// Round 5
// baseline (110.710 us; speedup 1.0000x reference)
//
#include <hip/hip_runtime.h>
#include <hip/hip_bf16.h>
#include <stdint.h>

#define EPS 1e-5f

constexpr int T_   = 2048;
constexpr int IN_  = 256;
constexpr int HID_ = 32;
constexpr int KB_  = 9728;   // Bfull row length (u16)
// Bfull k-map: [0,8192) W2 flat (k=i*32+h); [8192,8448) b2; [8448,9472) Q2;
// [9472,9504) 2*P2; [9504] qb2; [9536,9568) S2; [9568] sb2; rest zeros.

typedef __attribute__((ext_vector_type(8))) short short8;
typedef __attribute__((ext_vector_type(4))) float f32x4;
typedef __attribute__((ext_vector_type(2))) float f32x2;

union AB { unsigned int u[4]; short8 s8; };

typedef const __attribute__((address_space(1))) uint32_t gas_u32;
typedef __attribute__((address_space(3))) uint32_t las_u32;

static __device__ __forceinline__ void gll16(const void* src, void* dst) {
    __builtin_amdgcn_global_load_lds((gas_u32*)src, (las_u32*)dst, 16, 0, 0);
}
static __device__ __forceinline__ unsigned short f2b(float f) {
    __hip_bfloat16 h = __float2bfloat16(f);
    return *reinterpret_cast<unsigned short*>(&h);
}
static __device__ __forceinline__ unsigned int cvtpk(float lo, float hi) {
    unsigned int r;
    asm("v_cvt_pk_bf16_f32 %0, %1, %2" : "=v"(r) : "v"(lo), "v"(hi));
    return r;
}

// ===========================================================================
// k_pre: fused prep (blocks 0..255, one per o) + ka (blocks 256..767, 4 tok)
// ===========================================================================
__device__ void prep_body(int o, const float* __restrict__ w2,
                          const float* __restrict__ b2,
                          unsigned short* __restrict__ Bf, char* smem)
{
    float* w2s = (float*)smem;            // 8192 f
    float* b2s = w2s + 8192;              // 256 f
    float* pP  = b2s + 256;               // 256 f  [s*32+h]
    float* pS  = pP + 256;                // 256 f
    float* pB  = pS + 256;                // 8 f
    float* pQ  = pB + 8;                  // 8 f

    const int tid = threadIdx.x, lane = tid & 63, wave = tid >> 6;
    const int c = lane & 15, g = lane >> 4;
    const float* w2o = w2 + (size_t)o * 8192;

    #pragma unroll
    for (int q = 0; q < 8; ++q) {
        int I = wave * 8 + q;
        gll16(w2o + I * 256 + lane * 4, w2s + I * 256);
    }
    if (wave == 0) gll16(b2 + (size_t)o * 256 + lane * 4, b2s);
    asm volatile("s_waitcnt vmcnt(0)" ::: "memory");
    __syncthreads();

    unsigned short* row = Bf + (size_t)o * KB_;

    { // W2 flat bf16 [0,8192)
        const float* src = w2s + tid * 32;
        unsigned int pk[16];
        #pragma unroll
        for (int d = 0; d < 16; ++d) pk[d] = cvtpk(src[2 * d], src[2 * d + 1]);
        uint4* dst = (uint4*)(row + tid * 32);
        dst[0] = make_uint4(pk[0], pk[1], pk[2], pk[3]);
        dst[1] = make_uint4(pk[4], pk[5], pk[6], pk[7]);
        dst[2] = make_uint4(pk[8], pk[9], pk[10], pk[11]);
        dst[3] = make_uint4(pk[12], pk[13], pk[14], pk[15]);
    }
    row[8192 + tid] = f2b(b2s[tid]);   // b2 [8192,8448)

    // Q2 quadrant per wave: Q2[h,h'] = sum_i W2[i,h] W2[i,h']
    {
        const int qr = wave >> 1, qc = wave & 1;
        f32x4 acc = {0, 0, 0, 0};
        #pragma unroll
        for (int kk = 0; kk < 8; ++kk) {
            AB af, bff;
            #pragma unroll
            for (int d = 0; d < 4; ++d) {
                int i0 = kk * 32 + g * 8 + 2 * d;
                af.u[d] = cvtpk(w2s[i0 * 32 + qr * 16 + c],
                                w2s[(i0 + 1) * 32 + qr * 16 + c]);
                bff.u[d] = (qr == qc) ? af.u[d]
                         : cvtpk(w2s[i0 * 32 + qc * 16 + c],
                                 w2s[(i0 + 1) * 32 + qc * 16 + c]);
            }
            acc = __builtin_amdgcn_mfma_f32_16x16x32_bf16(af.s8, bff.s8, acc, 0, 0, 0);
        }
        #pragma unroll
        for (int j = 0; j < 4; ++j)
            row[8448 + (qr * 16 + g * 4 + j) * 32 + qc * 16 + c] = f2b(acc[j]);
    }

    { // partial P2/S2 + b2 sums
        int h = tid & 31, s = tid >> 5;
        float pa = 0.f, sa = 0.f;
        for (int i = s * 32; i < s * 32 + 32; ++i) {
            float wv = w2s[i * 32 + h];
            pa += wv * b2s[i];
            sa += wv;
        }
        pP[s * 32 + h] = pa; pS[s * 32 + h] = sa;
        if (h == 0) {
            float sb = 0.f, qb = 0.f;
            for (int i = s * 32; i < s * 32 + 32; ++i) {
                float bv = b2s[i]; sb += bv; qb += bv * bv;
            }
            pB[s] = sb; pQ[s] = qb;
        }
    }
    __syncthreads();
    if (tid < 32) {
        float p = 0.f, sv = 0.f;
        #pragma unroll
        for (int s2 = 0; s2 < 8; ++s2) { p += pP[s2 * 32 + tid]; sv += pS[s2 * 32 + tid]; }
        row[9472 + tid] = f2b(2.0f * p);
        row[9536 + tid] = f2b(sv);
    } else if (tid == 32) {
        float sb = 0.f;
        #pragma unroll
        for (int s2 = 0; s2 < 8; ++s2) sb += pB[s2];
        row[9568] = f2b(sb);
    } else if (tid == 33) {
        float qb = 0.f;
        #pragma unroll
        for (int s2 = 0; s2 < 8; ++s2) qb += pQ[s2];
        row[9504] = f2b(qb);
    }
    if (tid < 31) row[9505 + tid] = 0;
    { int z = tid - 31; if (z >= 0 && z < 31) row[9569 + z] = 0; }
    { int z = tid - 62; if (z >= 0 && z < 128) row[9600 + z] = 0; }
}

__device__ void ka_body(int tb, const float* __restrict__ x,
                        const float* __restrict__ w1, const float* __restrict__ b1,
                        const float* __restrict__ u1, const float* __restrict__ c1,
                        const float* __restrict__ u2, const float* __restrict__ c2,
                        unsigned short* __restrict__ xbf,
                        unsigned short* __restrict__ hwbf,
                        float* __restrict__ sx_out,
                        float* __restrict__ bln_out, char* smem)
{
    const int tid = threadIdx.x, l = tid & 63, wave = tid >> 6;
    const int t = tb * 4 + wave;

    float* xs = (float*)smem + wave * 288;   // 256 + 32 per wave
    float* hb = xs + 256;

    float4 x4 = reinterpret_cast<const float4*>(x + (size_t)t * 256)[l];
    reinterpret_cast<float4*>(xs)[l] = x4;

    float s = x4.x + x4.y + x4.z + x4.w;
    #pragma unroll
    for (int off = 32; off > 0; off >>= 1) s += __shfl_xor(s, off);
    if (l == 0) sx_out[t] = s;

    {
        ushort4 ux;
        ux.x = f2b(x4.x); ux.y = f2b(x4.y); ux.z = f2b(x4.z); ux.w = f2b(x4.w);
        *reinterpret_cast<ushort4*>(xbf + (size_t)t * 256 + l * 4) = ux;
    }
    __syncthreads();

    const float* wrow = (l < 32) ? (w1 + (size_t)l * 256) : (u1 + (size_t)(l - 32) * 256);
    float acc = (l < 32) ? b1[l] : c1[l - 32];
    #pragma unroll 8
    for (int i = 0; i < 256; i += 4) {
        float4 w = *reinterpret_cast<const float4*>(wrow + i);
        acc += w.x * xs[i] + w.y * xs[i + 1] + w.z * xs[i + 2] + w.w * xs[i + 3];
    }
    if (l < 32) hwbf[(size_t)t * 32 + l] = f2b(acc);
    else        hb[l - 32] = acc;
    __syncthreads();

    float bv[4];
    #pragma unroll
    for (int r = 0; r < 4; ++r) {
        const int o = l * 4 + r;
        const float* urow = u2 + (size_t)o * 32;
        float a = c2[o];
        #pragma unroll
        for (int h = 0; h < 32; h += 4) {
            float4 u = *reinterpret_cast<const float4*>(urow + h);
            a += u.x * hb[h] + u.y * hb[h + 1] + u.z * hb[h + 2] + u.w * hb[h + 3];
        }
        bv[r] = a;
    }
    float ss = bv[0] + bv[1] + bv[2] + bv[3];
    float qq = bv[0] * bv[0] + bv[1] * bv[1] + bv[2] * bv[2] + bv[3] * bv[3];
    #pragma unroll
    for (int off = 32; off > 0; off >>= 1) {
        ss += __shfl_xor(ss, off);
        qq += __shfl_xor(qq, off);
    }
    const float mu  = ss * (1.0f / 256.f);
    const float var = qq * (1.0f / 256.f) - mu * mu;
    const float inv = rsqrtf(var + EPS);
    #pragma unroll
    for (int r = 0; r < 4; ++r)
        bln_out[(size_t)t * 256 + l * 4 + r] = (bv[r] - mu) * inv;
}

__global__ __launch_bounds__(256)
void k_pre(const float* __restrict__ x,
           const float* __restrict__ w1, const float* __restrict__ b1,
           const float* __restrict__ w2, const float* __restrict__ b2,
           const float* __restrict__ u1, const float* __restrict__ c1,
           const float* __restrict__ u2, const float* __restrict__ c2,
           unsigned short* __restrict__ Bf,
           unsigned short* __restrict__ xbf,
           unsigned short* __restrict__ hwbf,
           float* __restrict__ sx, float* __restrict__ bln)
{
    __shared__ __align__(16) char smem[36992];
    const int b = blockIdx.x;
    if (b < 256) prep_body(b, w2, b2, Bf, smem);
    else         ka_body(b - 256, x, w1, b1, u1, c1, u2, c2, xbf, hwbf, sx, bln, smem);
}

// ===========================================================================
// k_main: NO LDS, NO barriers. 512 blocks x 4 waves; wave = 16t x 16o.
// B-fragments read direct from global (L1/L2) with 1-chunk register prefetch.
// ===========================================================================
__global__ __launch_bounds__(256)
void k_main(const unsigned short* __restrict__ Bf,
            const unsigned short* __restrict__ xbf,
            const unsigned short* __restrict__ hwbf,
            const float* __restrict__ sx,
            const float* __restrict__ bln,
            float* __restrict__ y)
{
    const int tid = threadIdx.x, lane = tid & 63, wave = tid >> 6;
    const int c = lane & 15, g = lane >> 4;
    const int b = blockIdx.x;
    const int o_tile = (b & 7) * 2 + ((b >> 3) & 1);   // 0..15, XCD-pinned
    const int t_tile = b >> 4;                          // 0..31
    const int orow0  = o_tile * 16;
    const int tw0    = t_tile * 64 + wave * 16;

    const unsigned short* Brow = Bf + (size_t)(orow0 + c) * KB_ + g * 8;
    const unsigned short* xrow = xbf + (size_t)(tw0 + c) * 256;
    const unsigned short* hrow = hwbf + (size_t)(tw0 + c) * 32;

    // hw fragment (A rows = tokens; lane c = token, k = g*8+v)
    AB hp;
    {
        uint4 v = *(const uint4*)(hrow + g * 8);
        hp.u[0] = v.x; hp.u[1] = v.y; hp.u[2] = v.z; hp.u[3] = v.w;
    }
    f32x2 hwp[4];
    #pragma unroll
    for (int d = 0; d < 4; ++d) {
        hwp[d].x = __uint_as_float(hp.u[d] << 16);
        hwp[d].y = __uint_as_float(hp.u[d] & 0xFFFF0000u);
    }

    f32x4 dw = {0,0,0,0}, qq = {0,0,0,0}, sw = {0,0,0,0};

    auto loadB = [&](int cc, short8* dst) {
        const unsigned short* p = Brow + cc * 128;
        #pragma unroll
        for (int u = 0; u < 4; ++u) dst[u] = *(const short8*)(p + u * 32);
    };
    auto buildA = [&](float xv, AB& a) {
        f32x2 xv2 = {xv, xv};
        #pragma unroll
        for (int d = 0; d < 4; ++d) {
            f32x2 pr = hwp[d] * xv2;
            a.u[d] = cvtpk(pr.x, pr.y);
        }
    };

    short8 BA[4], BB[4];
    uint2 xqA, xqB;
    loadB(0, BA);
    xqA = *(const uint2*)(xrow);

    // ---- MODE X: cc 0..63, dw += (x_i * hw) x W2 ----
    auto stepX = [&](int cc, short8* cur, short8* nxt, uint2 xqc, uint2& xqn) {
        loadB(cc + 1, nxt);
        xqn = *(const uint2*)(xrow + (cc + 1) * 4);
        #pragma unroll
        for (int u = 0; u < 4; ++u) {
            unsigned int d = (u & 2) ? xqc.y : xqc.x;
            float xv = __uint_as_float((u & 1) ? (d & 0xFFFF0000u) : (d << 16));
            AB a; buildA(xv, a);
            dw = __builtin_amdgcn_mfma_f32_16x16x32_bf16(a.s8, cur[u], dw, 0, 0, 0);
        }
    };
    for (int p = 0; p < 32; ++p) {
        stepX(2 * p,     BA, BB, xqA, xqB);
        stepX(2 * p + 1, BB, BA, xqB, xqA);
    }

    // ---- MODE DX: cc 64,65, dw += x-frag x b2 ----
    {
        loadB(65, BB);
        #pragma unroll
        for (int u = 0; u < 4; ++u) {
            AB a; a.s8 = *(const short8*)(xrow + u * 32 + g * 8);
            dw = __builtin_amdgcn_mfma_f32_16x16x32_bf16(a.s8, BA[u], dw, 0, 0, 0);
        }
        loadB(66, BA);
        #pragma unroll
        for (int u = 0; u < 4; ++u) {
            AB a; a.s8 = *(const short8*)(xrow + 128 + u * 32 + g * 8);
            dw = __builtin_amdgcn_mfma_f32_16x16x32_bf16(a.s8, BB[u], dw, 0, 0, 0);
        }
    }

    // ---- MODE HW: cc 66..73, qq += (hw_h * hw) x Q2 ----
    #pragma unroll
    for (int q = 0; q < 8; ++q) {
        const int cc = 66 + q;
        short8* cur = (q & 1) ? BB : BA;
        short8* nxt = (q & 1) ? BA : BB;
        loadB(cc + 1, nxt);
        uint2 hq = *(const uint2*)(hrow + q * 4);
        #pragma unroll
        for (int u = 0; u < 4; ++u) {
            unsigned int d = (u & 2) ? hq.y : hq.x;
            float hv = __uint_as_float((u & 1) ? (d & 0xFFFF0000u) : (d << 16));
            AB a; buildA(hv, a);
            qq = __builtin_amdgcn_mfma_f32_16x16x32_bf16(a.s8, cur[u], qq, 0, 0, 0);
        }
    }

    // ---- cc 74: 2*P2 | qb2 | S2 | sb2 (cur = BA) ----
    {
        AB e0;
        e0.u[0] = (g == 0) ? 0x3F80u : 0u;
        e0.u[1] = 0; e0.u[2] = 0; e0.u[3] = 0;
        qq = __builtin_amdgcn_mfma_f32_16x16x32_bf16(hp.s8, BA[0], qq, 0, 0, 0);
        qq = __builtin_amdgcn_mfma_f32_16x16x32_bf16(e0.s8, BA[1], qq, 0, 0, 0);
        sw = __builtin_amdgcn_mfma_f32_16x16x32_bf16(hp.s8, BA[2], sw, 0, 0, 0);
        sw = __builtin_amdgcn_mfma_f32_16x16x32_bf16(e0.s8, BA[3], sw, 0, 0, 0);
    }

    // ---- epilogue: fused LN + y ----
    const int o = orow0 + c;
    #pragma unroll
    for (int j = 0; j < 4; ++j) {
        int t = tw0 + g * 4 + j;
        float muv = sw[j] * (1.f / 256.f);
        float varv = qq[j] * (1.f / 256.f) - muv * muv;
        float inv = rsqrtf(varv + EPS);
        y[(size_t)t * 256 + o] = inv * (dw[j] - muv * sx[t]) + bln[(size_t)t * 256 + o];
    }
}

// ---------------------------------------------------------------------------
extern "C" void kernel_launch(void* const* d_in, const int* in_sizes, int n_in,
                              void* d_out, int out_size, void* d_ws, size_t ws_size,
                              hipStream_t stream)
{
    (void)in_sizes; (void)n_in; (void)out_size; (void)ws_size;
    const float* x  = (const float*)d_in[0];
    const float* w1 = (const float*)d_in[1];
    const float* b1 = (const float*)d_in[2];
    const float* w2 = (const float*)d_in[3];
    const float* b2 = (const float*)d_in[4];
    const float* u1 = (const float*)d_in[5];
    const float* c1 = (const float*)d_in[6];
    const float* u2 = (const float*)d_in[7];
    const float* c2 = (const float*)d_in[8];
    float* y = (float*)d_out;

    char* ws = (char*)d_ws;
    unsigned short* Bfull = (unsigned short*)(ws);            // 256*9728*2 = 4,980,736
    unsigned short* xbf   = (unsigned short*)(ws + 4980736);  // 2048*256*2 = 1,048,576
    unsigned short* hwbf  = (unsigned short*)(ws + 6029312);  // 2048*32*2  =   131,072
    float*          sxp   = (float*)(ws + 6160384);           // 2048*4     =     8,192
    float*          blnp  = (float*)(ws + 6168576);           // 2048*256*4 = 2,097,152 -> 8,265,728

    k_pre<<<768, 256, 0, stream>>>(x, w1, b1, w2, b2, u1, c1, u2, c2,
                                   Bfull, xbf, hwbf, sxp, blnp);
    k_main<<<512, 256, 0, stream>>>(Bfull, xbf, hwbf, sxp, blnp, y);
}

// Round 8
// 77.586 us; speedup vs baseline: 1.4269x; 1.4269x over previous
//
#include <hip/hip_runtime.h>
#include <hip/hip_bf16.h>
#include <stdint.h>

#define EPS 1e-5f

constexpr int T_   = 2048;
constexpr int IN_  = 256;
constexpr int HID_ = 32;
constexpr int XP   = 264;    // x row pad (u16)
constexpr int HP   = 40;     // hw row pad (u16)
constexpr int KB_  = 9728;   // Bfull row length (u16)
// Bfull k-map: [0,8192) W2 flat (k=i*32+h); [8192,8448) b2; [8448,9472) Q2;
// [9472,9504) 2*P2; [9504] qb2; [9536,9568) S2; [9568] sb2; rest zeros.

typedef __attribute__((ext_vector_type(8))) short short8;
typedef __attribute__((ext_vector_type(4))) float f32x4;

union AB { unsigned int u[4]; short8 s8; };

typedef const __attribute__((address_space(1))) uint32_t gas_u32;
typedef __attribute__((address_space(3))) uint32_t las_u32;

static __device__ __forceinline__ void gll16(const void* src, void* dst) {
    __builtin_amdgcn_global_load_lds((gas_u32*)src, (las_u32*)dst, 16, 0, 0);
}
static __device__ __forceinline__ unsigned short f2b(float f) {
    __hip_bfloat16 h = __float2bfloat16(f);
    return *reinterpret_cast<unsigned short*>(&h);
}
static __device__ __forceinline__ unsigned int cvtpk(float lo, float hi) {
    unsigned int r;
    asm("v_cvt_pk_bf16_f32 %0, %1, %2" : "=v"(r) : "v"(lo), "v"(hi));
    return r;
}

// ===========================================================================
// prep_body (R4-proven): per o — W2 flat bf16, b2 bf16, Q2 (MFMA), P2/S2/etc.
// ===========================================================================
__device__ void prep_body(int o, const float* __restrict__ w2,
                          const float* __restrict__ b2,
                          unsigned short* __restrict__ Bf, char* smem)
{
    float* w2s = (float*)smem;            // 8192 f
    float* b2s = w2s + 8192;              // 256 f
    float* pP  = b2s + 256;               // 256 f  [s*32+h]
    float* pS  = pP + 256;                // 256 f
    float* pB  = pS + 256;                // 8 f
    float* pQ  = pB + 8;                  // 8 f

    const int tid = threadIdx.x, lane = tid & 63, wave = tid >> 6;
    const int c = lane & 15, g = lane >> 4;
    const float* w2o = w2 + (size_t)o * 8192;

    #pragma unroll
    for (int q = 0; q < 8; ++q) {
        int I = wave * 8 + q;
        gll16(w2o + I * 256 + lane * 4, w2s + I * 256);
    }
    if (wave == 0) gll16(b2 + (size_t)o * 256 + lane * 4, b2s);
    asm volatile("s_waitcnt vmcnt(0)" ::: "memory");
    __syncthreads();

    unsigned short* row = Bf + (size_t)o * KB_;

    { // W2 flat bf16 [0,8192)
        const float* src = w2s + tid * 32;
        unsigned int pk[16];
        #pragma unroll
        for (int d = 0; d < 16; ++d) pk[d] = cvtpk(src[2 * d], src[2 * d + 1]);
        uint4* dst = (uint4*)(row + tid * 32);
        dst[0] = make_uint4(pk[0], pk[1], pk[2], pk[3]);
        dst[1] = make_uint4(pk[4], pk[5], pk[6], pk[7]);
        dst[2] = make_uint4(pk[8], pk[9], pk[10], pk[11]);
        dst[3] = make_uint4(pk[12], pk[13], pk[14], pk[15]);
    }
    row[8192 + tid] = f2b(b2s[tid]);   // b2 [8192,8448)

    // Q2 quadrant per wave: Q2[h,h'] = sum_i W2[i,h] W2[i,h']
    {
        const int qr = wave >> 1, qc = wave & 1;
        f32x4 acc = {0, 0, 0, 0};
        #pragma unroll
        for (int kk = 0; kk < 8; ++kk) {
            AB af, bff;
            #pragma unroll
            for (int d = 0; d < 4; ++d) {
                int i0 = kk * 32 + g * 8 + 2 * d;
                af.u[d] = cvtpk(w2s[i0 * 32 + qr * 16 + c],
                                w2s[(i0 + 1) * 32 + qr * 16 + c]);
                bff.u[d] = (qr == qc) ? af.u[d]
                         : cvtpk(w2s[i0 * 32 + qc * 16 + c],
                                 w2s[(i0 + 1) * 32 + qc * 16 + c]);
            }
            acc = __builtin_amdgcn_mfma_f32_16x16x32_bf16(af.s8, bff.s8, acc, 0, 0, 0);
        }
        #pragma unroll
        for (int j = 0; j < 4; ++j)
            row[8448 + (qr * 16 + g * 4 + j) * 32 + qc * 16 + c] = f2b(acc[j]);
    }

    { // partial P2/S2 + b2 sums
        int h = tid & 31, s = tid >> 5;
        float pa = 0.f, sa = 0.f;
        for (int i = s * 32; i < s * 32 + 32; ++i) {
            float wv = w2s[i * 32 + h];
            pa += wv * b2s[i];
            sa += wv;
        }
        pP[s * 32 + h] = pa; pS[s * 32 + h] = sa;
        if (h == 0) {
            float sb = 0.f, qb = 0.f;
            for (int i = s * 32; i < s * 32 + 32; ++i) {
                float bv = b2s[i]; sb += bv; qb += bv * bv;
            }
            pB[s] = sb; pQ[s] = qb;
        }
    }
    __syncthreads();
    if (tid < 32) {
        float p = 0.f, sv = 0.f;
        #pragma unroll
        for (int s2 = 0; s2 < 8; ++s2) { p += pP[s2 * 32 + tid]; sv += pS[s2 * 32 + tid]; }
        row[9472 + tid] = f2b(2.0f * p);
        row[9536 + tid] = f2b(sv);
    } else if (tid == 32) {
        float sb = 0.f;
        #pragma unroll
        for (int s2 = 0; s2 < 8; ++s2) sb += pB[s2];
        row[9568] = f2b(sb);
    } else if (tid == 33) {
        float qb = 0.f;
        #pragma unroll
        for (int s2 = 0; s2 < 8; ++s2) qb += pQ[s2];
        row[9504] = f2b(qb);
    }
    if (tid < 31) row[9505 + tid] = 0;
    { int z = tid - 31; if (z >= 0 && z < 31) row[9569 + z] = 0; }
    { int z = tid - 62; if (z >= 0 && z < 128) row[9600 + z] = 0; }
}

// ===========================================================================
// ka_body (R5-proven structure, R4 padded outputs): 4 tokens per 256-thr block
// ===========================================================================
__device__ void ka_body(int tb, const float* __restrict__ x,
                        const float* __restrict__ w1, const float* __restrict__ b1,
                        const float* __restrict__ u1, const float* __restrict__ c1,
                        const float* __restrict__ u2, const float* __restrict__ c2,
                        unsigned short* __restrict__ xp_out,    // [T][XP]
                        unsigned short* __restrict__ hwbf_out,  // [T][HP]
                        float* __restrict__ sx_out,             // [T]
                        float* __restrict__ bln_out,            // [T][256]
                        char* smem)
{
    const int tid = threadIdx.x, l = tid & 63, wave = tid >> 6;
    const int t = tb * 4 + wave;

    float* xs = (float*)smem + wave * 288;   // 256 + 32 per wave
    float* hb = xs + 256;

    float4 x4 = reinterpret_cast<const float4*>(x + (size_t)t * 256)[l];
    reinterpret_cast<float4*>(xs)[l] = x4;

    float s = x4.x + x4.y + x4.z + x4.w;
    #pragma unroll
    for (int off = 32; off > 0; off >>= 1) s += __shfl_xor(s, off);
    if (l == 0) sx_out[t] = s;

    {
        ushort4 ux;
        ux.x = f2b(x4.x); ux.y = f2b(x4.y); ux.z = f2b(x4.z); ux.w = f2b(x4.w);
        *reinterpret_cast<ushort4*>(xp_out + (size_t)t * XP + l * 4) = ux;
    }
    __syncthreads();

    const float* wrow = (l < 32) ? (w1 + (size_t)l * 256) : (u1 + (size_t)(l - 32) * 256);
    float acc = (l < 32) ? b1[l] : c1[l - 32];
    #pragma unroll 8
    for (int i = 0; i < 256; i += 4) {
        float4 w = *reinterpret_cast<const float4*>(wrow + i);
        acc += w.x * xs[i] + w.y * xs[i + 1] + w.z * xs[i + 2] + w.w * xs[i + 3];
    }
    if (l < 32) hwbf_out[(size_t)t * HP + l] = f2b(acc);
    else        hb[l - 32] = acc;
    __syncthreads();

    float bv[4];
    #pragma unroll
    for (int r = 0; r < 4; ++r) {
        const int oo = l * 4 + r;
        const float* urow = u2 + (size_t)oo * 32;
        float a = c2[oo];
        #pragma unroll
        for (int h = 0; h < 32; h += 4) {
            float4 u = *reinterpret_cast<const float4*>(urow + h);
            a += u.x * hb[h] + u.y * hb[h + 1] + u.z * hb[h + 2] + u.w * hb[h + 3];
        }
        bv[r] = a;
    }
    float ss = bv[0] + bv[1] + bv[2] + bv[3];
    float qs = bv[0]*bv[0] + bv[1]*bv[1] + bv[2]*bv[2] + bv[3]*bv[3];
    #pragma unroll
    for (int off = 32; off > 0; off >>= 1) {
        ss += __shfl_xor(ss, off);
        qs += __shfl_xor(qs, off);
    }
    const float mu  = ss * (1.0f / 256.f);
    const float var = qs * (1.0f / 256.f) - mu * mu;
    const float inv = rsqrtf(var + EPS);
    #pragma unroll
    for (int r = 0; r < 4; ++r)
        bln_out[(size_t)t * 256 + l * 4 + r] = (bv[r] - mu) * inv;
}

__global__ __launch_bounds__(256)
void k_pre(const float* __restrict__ x,
           const float* __restrict__ w1, const float* __restrict__ b1,
           const float* __restrict__ w2, const float* __restrict__ b2,
           const float* __restrict__ u1, const float* __restrict__ c1,
           const float* __restrict__ u2, const float* __restrict__ c2,
           unsigned short* __restrict__ Bf,
           unsigned short* __restrict__ xpad,
           unsigned short* __restrict__ hwbf,
           float* __restrict__ sx, float* __restrict__ bln)
{
    __shared__ __align__(16) char smem[35904];
    const int b = blockIdx.x;
    if (b < 256) prep_body(b, w2, b2, Bf, smem);
    else         ka_body(b - 256, x, w1, b1, u1, c1, u2, c2, xpad, hwbf, sx, bln, smem);
}

// ===========================================================================
// k_main (R4-proven algebra, 16-token waves for 2 blocks/CU):
// block = 16t x 64o, 4 waves; wave = 16t x 16o, OWNS its 16 B-rows.
// No barriers in K-loop: per-wave triple-buffered global_load_lds staging
// (counted vmcnt), B-fragments register-prefetched one chunk ahead.
// ===========================================================================
__global__ __launch_bounds__(256, 2)
void k_main(const unsigned short* __restrict__ Bf,
            const unsigned short* __restrict__ xpad,
            const unsigned short* __restrict__ hwbf,
            const float* __restrict__ sx,
            const float* __restrict__ bln,
            float* __restrict__ y)
{
    __shared__ __align__(16) unsigned short x_sh[16 * XP];     //  8448 B
    __shared__ __align__(16) unsigned short hw_sh[16 * HP];    //  1280 B
    __shared__ __align__(16) unsigned short Bb[3][4][2048];    // 49152 B

    const int tid = threadIdx.x, lane = tid & 63, wave = tid >> 6;
    const int c = lane & 15, g = lane >> 4;
    const int b = blockIdx.x;
    // XCD swizzle: b&7 ~ XCD; o_tile pinned to an XCD pair (1.25MB B-slice L2-resident)
    const int o_tile = (b & 7) >> 1;                 // 0..3
    const int t_tile = ((b >> 3) << 1) | (b & 1);    // 0..127 (bijective)
    const int t0 = t_tile * 16;
    const int orow0 = o_tile * 64 + wave * 16;       // wave's first global o

    // ---- prologue: cooperative x/hw staging, ONE barrier ----
    {
        const char* gp = (const char*)(xpad + (size_t)t0 * XP);
        for (int off = wave * 1024; off < 16 * XP * 2; off += 4096)
            if (off + lane * 16 < 16 * XP * 2)
                gll16(gp + off + lane * 16, ((char*)x_sh) + off);
        const char* gh = (const char*)(hwbf + (size_t)t0 * HP);
        for (int off = wave * 1024; off < 16 * HP * 2; off += 4096)
            if (off + lane * 16 < 16 * HP * 2)
                gll16(gh + off + lane * 16, ((char*)hw_sh) + off);
    }
    asm volatile("s_waitcnt vmcnt(0)" ::: "memory");
    __syncthreads();

    // ---- wave-private B staging (source-side XOR swizzle, linear LDS dest) ----
    const unsigned short* BfW = Bf + (size_t)orow0 * KB_;
    unsigned short* BbW[3] = { &Bb[0][wave][0], &Bb[1][wave][0], &Bb[2][wave][0] };
    auto stageB = [&](int cc, int buf) {
        #pragma unroll
        for (int q = 0; q < 4; ++q) {
            int r  = q * 4 + (lane >> 4);            // local B row 0..15
            int su = (lane & 15) ^ (r & 7);          // pre-swizzled source slot
            gll16(BfW + (size_t)r * KB_ + cc * 128 + su * 8,
                  BbW[buf] + q * 512 + lane * 8);
        }
    };
    auto readB = [&](int buf, short8* dst) {
        const unsigned short* base = &Bb[buf][wave][c * 128];
        #pragma unroll
        for (int u = 0; u < 4; ++u)
            dst[u] = *(const short8*)&base[((u * 4 + g) ^ (c & 7)) * 8];
    };

    // ---- hw fragment (constant over K) ----
    AB hp0;
    {
        uint4 v0 = *(const uint4*)&hw_sh[c * HP + g * 8];
        hp0.u[0] = v0.x; hp0.u[1] = v0.y; hp0.u[2] = v0.z; hp0.u[3] = v0.w;
    }
    float hwf0[8];
    #pragma unroll
    for (int d = 0; d < 4; ++d) {
        hwf0[2 * d]     = __uint_as_float(hp0.u[d] << 16);
        hwf0[2 * d + 1] = __uint_as_float(hp0.u[d] & 0xFFFF0000u);
    }

    f32x4 dw0 = {0,0,0,0}, qq0 = {0,0,0,0}, sw0 = {0,0,0,0};

    // ---- pipeline prologue: 3 chunks in flight, chunk 0 frags in regs ----
    stageB(0, 0); stageB(1, 1); stageB(2, 2);
    asm volatile("s_waitcnt vmcnt(8)" ::: "memory");   // chunk 0 staged
    short8 cur[4];
    readB(0, cur);

    const int xrow0 = c * XP;
    const int hrow0 = c * HP;

    for (int cc = 0; cc < 73; ++cc) {
        asm volatile("s_waitcnt vmcnt(4)" ::: "memory");   // chunk cc+1 staged
        asm volatile("s_waitcnt lgkmcnt(0)" ::: "memory"); // buf[cc%3] reads retired
        if (cc <= 71) stageB(cc + 3, (cc + 3) % 3);        // overwrite buf[cc%3]
        short8 nxt[4];
        readB((cc + 1) % 3, nxt);

        if (cc < 64) {            // MODE X: dw += (x_i * hw) x W2
            uint2 xq0 = *(const uint2*)&x_sh[xrow0 + cc * 4];
            #pragma unroll
            for (int u = 0; u < 4; ++u) {
                unsigned int d0 = (u & 2) ? xq0.y : xq0.x;
                float xv0 = __uint_as_float((u & 1) ? (d0 & 0xFFFF0000u) : (d0 << 16));
                AB a0;
                #pragma unroll
                for (int d = 0; d < 4; ++d)
                    a0.u[d] = cvtpk(xv0 * hwf0[2 * d], xv0 * hwf0[2 * d + 1]);
                dw0 = __builtin_amdgcn_mfma_f32_16x16x32_bf16(a0.s8, cur[u], dw0, 0, 0, 0);
            }
        } else if (cc < 66) {     // MODE DX: dw += x-frag x b2
            #pragma unroll
            for (int u = 0; u < 4; ++u) {
                AB a0;
                a0.s8 = *(const short8*)&x_sh[xrow0 + (cc - 64) * 128 + u * 32 + g * 8];
                dw0 = __builtin_amdgcn_mfma_f32_16x16x32_bf16(a0.s8, cur[u], dw0, 0, 0, 0);
            }
        } else {                  // MODE HW: qq += (hw_hp * hw) x Q2
            uint2 hq0 = *(const uint2*)&hw_sh[hrow0 + (cc - 66) * 4];
            #pragma unroll
            for (int u = 0; u < 4; ++u) {
                unsigned int d0 = (u & 2) ? hq0.y : hq0.x;
                float hv0 = __uint_as_float((u & 1) ? (d0 & 0xFFFF0000u) : (d0 << 16));
                AB a0;
                #pragma unroll
                for (int d = 0; d < 4; ++d)
                    a0.u[d] = cvtpk(hv0 * hwf0[2 * d], hv0 * hwf0[2 * d + 1]);
                qq0 = __builtin_amdgcn_mfma_f32_16x16x32_bf16(a0.s8, cur[u], qq0, 0, 0, 0);
            }
        }
        #pragma unroll
        for (int u = 0; u < 4; ++u) cur[u] = nxt[u];
    }

    // ---- peeled cc=73 (last HW chunk) ----
    {
        asm volatile("s_waitcnt vmcnt(0)" ::: "memory");   // chunk 74 staged
        asm volatile("s_waitcnt lgkmcnt(0)" ::: "memory");
        short8 tl[4];
        readB(74 % 3, tl);
        uint2 hq0 = *(const uint2*)&hw_sh[hrow0 + 7 * 4];
        #pragma unroll
        for (int u = 0; u < 4; ++u) {
            unsigned int d0 = (u & 2) ? hq0.y : hq0.x;
            float hv0 = __uint_as_float((u & 1) ? (d0 & 0xFFFF0000u) : (d0 << 16));
            AB a0;
            #pragma unroll
            for (int d = 0; d < 4; ++d)
                a0.u[d] = cvtpk(hv0 * hwf0[2 * d], hv0 * hwf0[2 * d + 1]);
            qq0 = __builtin_amdgcn_mfma_f32_16x16x32_bf16(a0.s8, cur[u], qq0, 0, 0, 0);
        }
        #pragma unroll
        for (int u = 0; u < 4; ++u) cur[u] = tl[u];
    }

    // ---- peeled cc=74: 2*P2 | qb2 | S2 | sb2 ----
    {
        AB e0;
        e0.u[0] = (g == 0) ? 0x3F80u : 0u;
        e0.u[1] = 0; e0.u[2] = 0; e0.u[3] = 0;
        qq0 = __builtin_amdgcn_mfma_f32_16x16x32_bf16(hp0.s8, cur[0], qq0, 0, 0, 0);
        qq0 = __builtin_amdgcn_mfma_f32_16x16x32_bf16(e0.s8,  cur[1], qq0, 0, 0, 0);
        sw0 = __builtin_amdgcn_mfma_f32_16x16x32_bf16(hp0.s8, cur[2], sw0, 0, 0, 0);
        sw0 = __builtin_amdgcn_mfma_f32_16x16x32_bf16(e0.s8,  cur[3], sw0, 0, 0, 0);
    }

    // ---- epilogue: fused LN + y ----
    const int o = orow0 + c;
    #pragma unroll
    for (int j = 0; j < 4; ++j) {
        int t = t0 + g * 4 + j;
        float muv = sw0[j] * (1.f / 256.f);
        float varv = qq0[j] * (1.f / 256.f) - muv * muv;
        float inv = rsqrtf(varv + EPS);
        y[(size_t)t * 256 + o] = inv * (dw0[j] - muv * sx[t]) + bln[(size_t)t * 256 + o];
    }
}

// ---------------------------------------------------------------------------
extern "C" void kernel_launch(void* const* d_in, const int* in_sizes, int n_in,
                              void* d_out, int out_size, void* d_ws, size_t ws_size,
                              hipStream_t stream)
{
    (void)in_sizes; (void)n_in; (void)out_size; (void)ws_size;
    const float* x  = (const float*)d_in[0];
    const float* w1 = (const float*)d_in[1];
    const float* b1 = (const float*)d_in[2];
    const float* w2 = (const float*)d_in[3];
    const float* b2 = (const float*)d_in[4];
    const float* u1 = (const float*)d_in[5];
    const float* c1 = (const float*)d_in[6];
    const float* u2 = (const float*)d_in[7];
    const float* c2 = (const float*)d_in[8];
    float* y = (float*)d_out;

    char* ws = (char*)d_ws;
    unsigned short* Bfull = (unsigned short*)(ws);                 // 256*9728*2 = 4,980,736
    unsigned short* xpad  = (unsigned short*)(ws + 4980736);       // 2048*264*2 = 1,081,344
    unsigned short* hwbf  = (unsigned short*)(ws + 6062080);       // 2048*40*2  =   163,840
    float*          sxp   = (float*)(ws + 6225920);                // 2048*4
    float*          blnp  = (float*)(ws + 6234112);                // 2048*256*4 -> 8,331,264 total

    // fused pre-stage: blocks 0..255 = prep(o), blocks 256..767 = ka (4 tok each)
    k_pre<<<768, 256, 0, stream>>>(x, w1, b1, w2, b2, u1, c1, u2, c2,
                                   Bfull, xpad, hwbf, sxp, blnp);

    k_main<<<512, 256, 0, stream>>>(Bfull, xpad, hwbf, sxp, blnp, y);
}